// Round 8
// baseline (1135.440 us; speedup 1.0000x reference)
//
#include <hip/hip_runtime.h>
#include <math.h>

// ---------------- problem constants ----------------
#define NTRK   1500
#define BSZ    64
#define NTOT   (NTRK*BSZ)        // 96000 tracks
#define LHID   128
#define TSTEPS 6
#define HID    256

#define TPB    256               // prep kernel
#define TPBM   1024              // main kernel: 16 waves
#define MTRK   64                // tracks per block
#define NBLK   (NTOT/MTRK)       // 1500 blocks

// ws layout (in shorts / bf16 elements)
#define WHH0_OFF 0
#define WIH1_OFF 65536
#define WHH1_OFF 131072
#define W0B_OFF  196608          // mlp w0 cols 3..130 -> [256][128]
#define W1B_OFF  229376          // mlp w1 [256][256]
#define BX_OFF   294912          // L0 x+bias slice [512][8]: {wx0, wx1, bias, 0...}
#define WS_SHORTS 299008         // 584 KiB

// output layout (flat fp32, return order)
#define OUT1_OFF ((size_t)NTOT*HID)
#define OUT2_OFF (OUT1_OFF + (size_t)NTOT*(HID/2))
#define OUT3_OFF (OUT2_OFF + (size_t)NTOT)
#define OUT4_OFF (OUT3_OFF + (size_t)NTOT)

typedef __bf16 bf16x8 __attribute__((ext_vector_type(8)));
typedef float  f32x4  __attribute__((ext_vector_type(4)));
typedef float  f32x2  __attribute__((ext_vector_type(2)));

__device__ __forceinline__ unsigned short f2b(float f) {
    union { float f; unsigned u; } v; v.f = f;
    return (unsigned short)((v.u + 0x7FFF + ((v.u >> 16) & 1)) >> 16);
}
__device__ __forceinline__ float sigf(float x) { return 1.0f / (1.0f + __expf(-x)); }
__device__ __forceinline__ float tanhfast(float x) {
    float e = __expf(2.0f * x);
    return (e - 1.0f) / (e + 1.0f);
}

// ---------------- prep: fp32 -> bf16 weight repack into ws ----------------
__global__ __launch_bounds__(TPB)
void prep_kernel(const float* __restrict__ Whh0, const float* __restrict__ Wih1,
                 const float* __restrict__ Whh1, const float* __restrict__ w0,
                 const float* __restrict__ w1,  const float* __restrict__ Wih0,
                 const float* __restrict__ bih0, const float* __restrict__ bhh0,
                 unsigned short* __restrict__ ws)
{
    int i = blockIdx.x * TPB + threadIdx.x;
    if (i < 65536)            ws[WHH0_OFF + i] = f2b(Whh0[i]);
    else if (i < 131072)      ws[WIH1_OFF + (i - 65536)]  = f2b(Wih1[i - 65536]);
    else if (i < 196608)      ws[WHH1_OFF + (i - 131072)] = f2b(Whh1[i - 131072]);
    else if (i < 229376) { int j = i - 196608; int n = j >> 7, k = j & 127;
                           ws[W0B_OFF + j] = f2b(w0[n * 131 + 3 + k]); }
    else if (i < 294912)      ws[W1B_OFF + (i - 229376)]  = f2b(w1[i - 229376]);
    else if (i < WS_SHORTS) { int j = i - 294912; int n = j >> 3, k = j & 7;
                              float v = (k == 0) ? Wih0[2 * n]
                                      : (k == 1) ? Wih0[2 * n + 1]
                                      : (k == 2) ? (bih0[n] + bhh0[n]) : 0.0f;
                              ws[BX_OFF + j] = f2b(v); }
}

// A-layout LDS address (in shorts), K=128 (4 k-steps), M up to 64:
__device__ __forceinline__ int aoff4(int m, int k) {
    return (((m >> 4) * 4 + (k >> 5)) * 64 + ((k >> 3) & 3) * 16 + (m & 15)) * 8 + (k & 7);
}
// A-layout, K=256 (8 k-steps), M up to 64:
__device__ __forceinline__ int aoff8(int m, int k) {
    return (((m >> 4) * 8 + (k >> 5)) * 64 + ((k >> 3) & 3) * 16 + (m & 15)) * 8 + (k & 7);
}

// acc[mt][ti] += A(hA, 4 m-tiles)·B(Wb, K=128) for TI N-tiles rowb[ti]
template<int TI>
__device__ __forceinline__ void accumT(f32x4 (&acc)[4][TI],
                                       const unsigned short* __restrict__ Wb,
                                       const unsigned short* hA,
                                       const int (&rowb)[TI], int lane, int quad)
{
    #pragma unroll
    for (int kk = 0; kk < 4; ++kk) {
        bf16x8 a[4];
        #pragma unroll
        for (int mt = 0; mt < 4; ++mt)
            a[mt] = *(const bf16x8*)&hA[((mt * 4 + kk) * 64 + lane) * 8];
        #pragma unroll
        for (int ti = 0; ti < TI; ++ti) {
            bf16x8 b = *(const bf16x8*)&Wb[(size_t)rowb[ti] * 128 + kk * 32 + quad * 8];
            #pragma unroll
            for (int mt = 0; mt < 4; ++mt)
                acc[mt][ti] = __builtin_amdgcn_mfma_f32_16x16x32_bf16(a[mt], b, acc[mt][ti], 0, 0, 0);
        }
    }
}

__global__ __launch_bounds__(TPBM, 4)
void lstm_mlp_mfma(const float* __restrict__ tfeat,
                   const float* __restrict__ bih1, const float* __restrict__ bhh1,
                   const float* __restrict__ w0,  const float* __restrict__ b0,
                   const float* __restrict__ b1,
                   const unsigned short* __restrict__ wsb,
                   float* __restrict__ out)
{
    // LDS layout:
    //   h0_0/h0_1 : [0,16K) [16K,32K)   h0 ping-pong (A-layout, K=128)
    //   h1_0/h1_1 : [32K,48K) [48K,64K) h1 ping-pong
    //   xbh   : [65536,67072)       [64][12] bf16 trajectory
    //   f5    : [67072,69120)       [64][8] f32 features 0..4
    //   mhA   : alias [0,32K)       mlp hidden (A-layout, K=256)
    //   outb  : alias [0,66544)     epilogue staging, stride 260 (f5 preserved)
    __shared__ __align__(16) char smem[69120];
    unsigned short* h0_0 = (unsigned short*)smem;
    unsigned short* h0_1 = (unsigned short*)(smem + 16384);
    unsigned short* h1_0 = (unsigned short*)(smem + 32768);
    unsigned short* h1_1 = (unsigned short*)(smem + 49152);
    unsigned short* mhA  = (unsigned short*)smem;
    unsigned short* xbh  = (unsigned short*)(smem + 65536);
    float (*f5)[8]  = (float(*)[8])(smem + 67072);
    float* outb = (float*)smem;

    const int tid  = threadIdx.x;
    const int w    = tid >> 6;        // 16 waves
    const int wgrp = w >> 3;          // 0: layer-0 waves, 1: layer-1 waves
    const int wl   = w & 7;           // unit-tile index within layer group
    const int lane = tid & 63;
    const int col  = lane & 15;
    const int quad = lane >> 4;
    const int base = blockIdx.x * MTRK;

    // ---- stage per-track inputs (traj as bf16, feats 0..4 as f32) ----
    if (tid < MTRK * 12) {
        int tl = tid & 63, f = tid >> 6;
        int n = base + tl, b = n / NTRK, tt = n - b * NTRK;
        xbh[tl * 12 + f] = f2b(tfeat[(size_t)(b * 18 + 6 + f) * NTRK + tt]);
    }
    if (tid < MTRK * 5) {
        int tl = tid & 63, f = tid >> 6;
        int n = base + tl, b = n / NTRK, tt = n - b * NTRK;
        f5[tl][f] = tfeat[(size_t)(b * 18 + f) * NTRK + tt];
    }
    __syncthreads();

    const unsigned short* Whh0b = wsb + WHH0_OFF;
    const unsigned short* Wih1b = wsb + WIH1_OFF;
    const unsigned short* Whh1b = wsb + WHH1_OFF;
    const unsigned short* w0b   = wsb + W0B_OFF;
    const unsigned short* w1b   = wsb + W1B_OFF;
    const unsigned short* Bx    = wsb + BX_OFF;

    // this wave's gate rows (PyTorch order i,f,g,o) for its 16 units
    const int rows_ig[2] = { 0 * 128 + wl * 16 + col, 2 * 128 + wl * 16 + col };
    const int rows_fo[2] = { 1 * 128 + wl * 16 + col, 3 * 128 + wl * 16 + col };
    // layer-1 bias sums (only used on wgrp==1 path)
    const float bsig[2] = { bih1[rows_ig[0]] + bhh1[rows_ig[0]],
                            bih1[rows_ig[1]] + bhh1[rows_ig[1]] };
    const float bsfo[2] = { bih1[rows_fo[0]] + bhh1[rows_fo[0]],
                            bih1[rows_fo[1]] + bhh1[rows_fo[1]] };

    // c-state for this wave's layer (16 units x 64 tracks)
    f32x4 cst[4];
    #pragma unroll
    for (int mt = 0; mt < 4; ++mt)
        #pragma unroll
        for (int r = 0; r < 4; ++r) cst[mt][r] = 0.0f;

    const int u = wl * 16 + col;   // hidden unit this lane produces

    // Software-pipelined recurrence: 7 phases, ONE barrier each.
    //   phase p: L0-waves compute h0[p]   (read h0[p-1], write h0b[p&1])
    //            L1-waves compute h1[p-1] (read h0[p-1], h1[p-2], write h1b[(p-1)&1])
    for (int p = 0; p < TSTEPS + 1; ++p) {
        if (wgrp == 0) {
            if (p < TSTEPS) {
                const int t = p;
                unsigned short*       h0w = (t & 1) ? h0_1 : h0_0;
                const unsigned short* h0r = (t & 1) ? h0_0 : h0_1;

                // x+bias A-fragments (shared by both gate passes)
                bf16x8 ax[4];
                #pragma unroll
                for (int mt = 0; mt < 4; ++mt) {
                    bf16x8 a;
                    #pragma unroll
                    for (int j = 0; j < 8; ++j) a[j] = (__bf16)0.0f;
                    if (quad == 0) {
                        int m = mt * 16 + col;
                        a[0] = *(const __bf16*)&xbh[m * 12 + 2 * t];
                        a[1] = *(const __bf16*)&xbh[m * 12 + 2 * t + 1];
                        a[2] = (__bf16)1.0f;
                    }
                    ax[mt] = a;
                }

                f32x4 pig[4];
                {   // pass 1: gates i,g -> p = sig(i)*tanh(g)
                    f32x4 acc[4][2];
                    #pragma unroll
                    for (int ti = 0; ti < 2; ++ti) {
                        bf16x8 bx;
                        #pragma unroll
                        for (int j = 0; j < 8; ++j) bx[j] = (__bf16)0.0f;
                        if (quad == 0) bx = *(const bf16x8*)&Bx[rows_ig[ti] * 8];
                        #pragma unroll
                        for (int mt = 0; mt < 4; ++mt) {
                            f32x4 z = {0.0f, 0.0f, 0.0f, 0.0f};
                            acc[mt][ti] = __builtin_amdgcn_mfma_f32_16x16x32_bf16(ax[mt], bx, z, 0, 0, 0);
                        }
                    }
                    if (t > 0) accumT<2>(acc, Whh0b, h0r, rows_ig, lane, quad);
                    #pragma unroll
                    for (int mt = 0; mt < 4; ++mt)
                        #pragma unroll
                        for (int r = 0; r < 4; ++r)
                            pig[mt][r] = sigf(acc[mt][0][r]) * tanhfast(acc[mt][1][r]);
                }
                {   // pass 2: gates f,o -> c,h
                    f32x4 acc[4][2];
                    #pragma unroll
                    for (int ti = 0; ti < 2; ++ti) {
                        bf16x8 bx;
                        #pragma unroll
                        for (int j = 0; j < 8; ++j) bx[j] = (__bf16)0.0f;
                        if (quad == 0) bx = *(const bf16x8*)&Bx[rows_fo[ti] * 8];
                        #pragma unroll
                        for (int mt = 0; mt < 4; ++mt) {
                            f32x4 z = {0.0f, 0.0f, 0.0f, 0.0f};
                            acc[mt][ti] = __builtin_amdgcn_mfma_f32_16x16x32_bf16(ax[mt], bx, z, 0, 0, 0);
                        }
                    }
                    if (t > 0) accumT<2>(acc, Whh0b, h0r, rows_fo, lane, quad);
                    #pragma unroll
                    for (int mt = 0; mt < 4; ++mt)
                        #pragma unroll
                        for (int r = 0; r < 4; ++r) {
                            float cn = sigf(acc[mt][0][r]) * cst[mt][r] + pig[mt][r];
                            cst[mt][r] = cn;
                            int m = mt * 16 + quad * 4 + r;
                            h0w[aoff4(m, u)] = f2b(sigf(acc[mt][1][r]) * tanhfast(cn));
                        }
                }
            }
        } else {
            if (p >= 1) {
                const int s = p - 1;
                const unsigned short* h0r = (s & 1) ? h0_1 : h0_0;   // h0[s]
                unsigned short*       h1w = (s & 1) ? h1_1 : h1_0;
                const unsigned short* h1r = (s & 1) ? h1_0 : h1_1;   // h1[s-1]

                f32x4 pig[4];
                {   // pass 1: gates i,g
                    f32x4 acc[4][2];
                    #pragma unroll
                    for (int mt = 0; mt < 4; ++mt)
                        #pragma unroll
                        for (int r = 0; r < 4; ++r) {
                            acc[mt][0][r] = bsig[0];
                            acc[mt][1][r] = bsig[1];
                        }
                    accumT<2>(acc, Wih1b, h0r, rows_ig, lane, quad);
                    if (s > 0) accumT<2>(acc, Whh1b, h1r, rows_ig, lane, quad);
                    #pragma unroll
                    for (int mt = 0; mt < 4; ++mt)
                        #pragma unroll
                        for (int r = 0; r < 4; ++r)
                            pig[mt][r] = sigf(acc[mt][0][r]) * tanhfast(acc[mt][1][r]);
                }
                {   // pass 2: gates f,o -> c,h
                    f32x4 acc[4][2];
                    #pragma unroll
                    for (int mt = 0; mt < 4; ++mt)
                        #pragma unroll
                        for (int r = 0; r < 4; ++r) {
                            acc[mt][0][r] = bsfo[0];
                            acc[mt][1][r] = bsfo[1];
                        }
                    accumT<2>(acc, Wih1b, h0r, rows_fo, lane, quad);
                    if (s > 0) accumT<2>(acc, Whh1b, h1r, rows_fo, lane, quad);
                    #pragma unroll
                    for (int mt = 0; mt < 4; ++mt)
                        #pragma unroll
                        for (int r = 0; r < 4; ++r) {
                            float cn = sigf(acc[mt][0][r]) * cst[mt][r] + pig[mt][r];
                            cst[mt][r] = cn;
                            int m = mt * 16 + quad * 4 + r;
                            h1w[aoff4(m, u)] = f2b(sigf(acc[mt][1][r]) * tanhfast(cn));
                        }
                }
            }
        }
        __syncthreads();   // one barrier per phase
    }

    const unsigned short* h1f = h1_1;   // h1[TSTEPS-1], (5&1)=1 -> buffer 1

    // ---------- MLP layer A: mh = relu([f3, h1] @ w0^T + b0) ----------
    // 16 waves x one 16-row tile: rowm = w*16+col
    const int rowm = w * 16 + col;
    {
        f32x4 am[4][1];
        {
            float bm  = b0[rowm];
            float wf0 = w0[rowm * 131 + 0], wf1 = w0[rowm * 131 + 1], wf2 = w0[rowm * 131 + 2];
            #pragma unroll
            for (int mt = 0; mt < 4; ++mt)
                #pragma unroll
                for (int r = 0; r < 4; ++r) {
                    int m = mt * 16 + quad * 4 + r;
                    am[mt][0][r] = bm + f5[m][0] * wf0 + f5[m][1] * wf1 + f5[m][2] * wf2;
                }
        }
        const int rowa[1] = { rowm };
        accumT<1>(am, w0b, h1f, rowa, lane, quad);
        // mhA aliases the (dead) h0 buffers [0,32K); disjoint from h1f [48K,64K).
        #pragma unroll
        for (int mt = 0; mt < 4; ++mt)
            #pragma unroll
            for (int r = 0; r < 4; ++r) {
                int m = mt * 16 + quad * 4 + r;
                mhA[aoff8(m, rowm)] = f2b(fmaxf(am[mt][0][r], 0.0f));
            }
        __syncthreads();   // mh visible
    }

    // ---------- MLP layer B: out = mh @ w1^T + b1 ----------
    {
        f32x4 ao[4];
        {
            float bv = b1[rowm];
            #pragma unroll
            for (int mt = 0; mt < 4; ++mt)
                #pragma unroll
                for (int r = 0; r < 4; ++r) ao[mt][r] = bv;
        }
        #pragma unroll
        for (int kk = 0; kk < 8; ++kk) {
            bf16x8 a[4];
            #pragma unroll
            for (int mt = 0; mt < 4; ++mt)
                a[mt] = *(const bf16x8*)&mhA[((mt * 8 + kk) * 64 + lane) * 8];
            bf16x8 b = *(const bf16x8*)&w1b[(size_t)rowm * 256 + kk * 32 + quad * 8];
            #pragma unroll
            for (int mt = 0; mt < 4; ++mt)
                ao[mt] = __builtin_amdgcn_mfma_f32_16x16x32_bf16(a[mt], b, ao[mt], 0, 0, 0);
        }
        __syncthreads();   // all mhA reads complete; LDS reusable as outb

        // stage in LDS (stride 260 floats)
        #pragma unroll
        for (int mt = 0; mt < 4; ++mt)
            #pragma unroll
            for (int r = 0; r < 4; ++r)
                outb[(mt * 16 + quad * 4 + r) * 260 + rowm] = ao[mt][r];
        __syncthreads();

        // fully-coalesced nontemporal stores: 16 B/lane
        for (int i = tid; i < MTRK * 64; i += TPBM) {
            int row = i >> 6, c4 = (i & 63) << 2;
            f32x4 v = *(const f32x4*)&outb[row * 260 + c4];
            __builtin_nontemporal_store(v, (f32x4*)(out + (size_t)(base + row) * HID + c4));
        }
    }

    // ---------- fused pos encoding + passthrough ----------
    {
        const int tl = tid >> 4;          // 64 tracks x 16 threads
        const int ml = tid & 15;
        const int n  = base + tl;
        const float eta   = f5[tl][3];
        const float phi   = f5[tl][4];
        const float TWO_PI = 6.28318530717958647692f;
        float* o1 = out + OUT1_OFF + (size_t)n * (HID / 2);
        #pragma unroll
        for (int i = 0; i < 2; ++i) {
            int m = ml + i * 16;
            float inv = exp2f(-(float)m * (13.28771237954945f / 32.0f));
            float pe = eta * TWO_PI * inv;
            float pp = phi * TWO_PI * inv;
            f32x2 ve = { sinf(pe), cosf(pe) };
            f32x2 vp = { sinf(pp), cosf(pp) };
            __builtin_nontemporal_store(ve, (f32x2*)(o1 + 2 * m));
            __builtin_nontemporal_store(vp, (f32x2*)(o1 + 64 + 2 * m));
        }
        if (ml == 0) {
            __builtin_nontemporal_store(f5[tl][2], out + OUT2_OFF + n);
            __builtin_nontemporal_store(eta, out + OUT3_OFF + n);
            __builtin_nontemporal_store(phi, out + OUT4_OFF + n);
        }
    }
}

extern "C" void kernel_launch(void* const* d_in, const int* in_sizes, int n_in,
                              void* d_out, int out_size, void* d_ws, size_t ws_size,
                              hipStream_t stream)
{
    const float* tfeat = (const float*)d_in[0];
    const float* Wih0  = (const float*)d_in[1];
    const float* Whh0  = (const float*)d_in[2];
    const float* bih0  = (const float*)d_in[3];
    const float* bhh0  = (const float*)d_in[4];
    const float* Wih1  = (const float*)d_in[5];
    const float* Whh1  = (const float*)d_in[6];
    const float* bih1  = (const float*)d_in[7];
    const float* bhh1  = (const float*)d_in[8];
    const float* w0    = (const float*)d_in[9];
    const float* b0    = (const float*)d_in[10];
    const float* w1    = (const float*)d_in[11];
    const float* b1    = (const float*)d_in[12];
    float* out = (float*)d_out;
    unsigned short* wsb = (unsigned short*)d_ws;  // 584 KiB bf16 weights

    hipLaunchKernelGGL(prep_kernel, dim3(WS_SHORTS / TPB), dim3(TPB), 0, stream,
                       Whh0, Wih1, Whh1, w0, w1, Wih0, bih0, bhh0, wsb);
    hipLaunchKernelGGL(lstm_mlp_mfma, dim3(NBLK), dim3(TPBM), 0, stream,
                       tfeat, bih1, bhh1, w0, b0, b1, wsb, out);
}

// Round 9
// 876.596 us; speedup vs baseline: 1.2953x; 1.2953x over previous
//
#include <hip/hip_runtime.h>
#include <math.h>

// ---------------- problem constants ----------------
#define NTRK   1500
#define BSZ    64
#define NTOT   (NTRK*BSZ)        // 96000 tracks
#define LHID   128
#define TSTEPS 6
#define HID    256

#define TPB    256               // prep kernel
#define TPBM   512               // main kernel: 8 waves, 256 regs/wave
#define MTRK   64                // tracks per block
#define NBLK   (NTOT/MTRK)       // 1500 blocks

// ws layout (in shorts / bf16 elements)
#define WHH0_OFF 0
#define WIH1_OFF 65536
#define WHH1_OFF 131072
#define W0B_OFF  196608          // mlp w0 cols 3..130 -> [256][128]
#define W1B_OFF  229376          // mlp w1 [256][256]
#define BX_OFF   294912          // L0 x+bias slice [512][8]: {wx0, wx1, bias, 0...}
#define WS_SHORTS 299008         // 584 KiB

// output layout (flat fp32, return order)
#define OUT1_OFF ((size_t)NTOT*HID)
#define OUT2_OFF (OUT1_OFF + (size_t)NTOT*(HID/2))
#define OUT3_OFF (OUT2_OFF + (size_t)NTOT)
#define OUT4_OFF (OUT3_OFF + (size_t)NTOT)

typedef __bf16 bf16x8 __attribute__((ext_vector_type(8)));
typedef float  f32x4  __attribute__((ext_vector_type(4)));
typedef float  f32x2  __attribute__((ext_vector_type(2)));

__device__ __forceinline__ unsigned short f2b(float f) {
    union { float f; unsigned u; } v; v.f = f;
    return (unsigned short)((v.u + 0x7FFF + ((v.u >> 16) & 1)) >> 16);
}
__device__ __forceinline__ float sigf(float x) { return 1.0f / (1.0f + __expf(-x)); }
__device__ __forceinline__ float tanhfast(float x) {
    float e = __expf(2.0f * x);
    return (e - 1.0f) / (e + 1.0f);
}

// ---------------- prep: fp32 -> bf16 weight repack into ws ----------------
__global__ __launch_bounds__(TPB)
void prep_kernel(const float* __restrict__ Whh0, const float* __restrict__ Wih1,
                 const float* __restrict__ Whh1, const float* __restrict__ w0,
                 const float* __restrict__ w1,  const float* __restrict__ Wih0,
                 const float* __restrict__ bih0, const float* __restrict__ bhh0,
                 unsigned short* __restrict__ ws)
{
    int i = blockIdx.x * TPB + threadIdx.x;
    if (i < 65536)            ws[WHH0_OFF + i] = f2b(Whh0[i]);
    else if (i < 131072)      ws[WIH1_OFF + (i - 65536)]  = f2b(Wih1[i - 65536]);
    else if (i < 196608)      ws[WHH1_OFF + (i - 131072)] = f2b(Whh1[i - 131072]);
    else if (i < 229376) { int j = i - 196608; int n = j >> 7, k = j & 127;
                           ws[W0B_OFF + j] = f2b(w0[n * 131 + 3 + k]); }
    else if (i < 294912)      ws[W1B_OFF + (i - 229376)]  = f2b(w1[i - 229376]);
    else if (i < WS_SHORTS) { int j = i - 294912; int n = j >> 3, k = j & 7;
                              float v = (k == 0) ? Wih0[2 * n]
                                      : (k == 1) ? Wih0[2 * n + 1]
                                      : (k == 2) ? (bih0[n] + bhh0[n]) : 0.0f;
                              ws[BX_OFF + j] = f2b(v); }
}

// A-layout LDS address (in shorts), K=128 (4 k-steps), M up to 64:
__device__ __forceinline__ int aoff4(int m, int k) {
    return (((m >> 4) * 4 + (k >> 5)) * 64 + ((k >> 3) & 3) * 16 + (m & 15)) * 8 + (k & 7);
}
// A-layout, K=256 (8 k-steps), M up to 64:
__device__ __forceinline__ int aoff8(int m, int k) {
    return (((m >> 4) * 8 + (k >> 5)) * 64 + ((k >> 3) & 3) * 16 + (m & 15)) * 8 + (k & 7);
}

// acc[mt][ti] += A(hA, 4 m-tiles)·B(Wb, K=128) for TI N-tiles rowb[ti]
template<int TI>
__device__ __forceinline__ void accum4(f32x4 (&acc)[4][TI],
                                       const unsigned short* __restrict__ Wb,
                                       const unsigned short* hA,
                                       const int (&rowb)[TI], int lane, int quad)
{
    #pragma unroll
    for (int kk = 0; kk < 4; ++kk) {
        bf16x8 a[4];
        #pragma unroll
        for (int mt = 0; mt < 4; ++mt)
            a[mt] = *(const bf16x8*)&hA[((mt * 4 + kk) * 64 + lane) * 8];
        #pragma unroll
        for (int ti = 0; ti < TI; ++ti) {
            bf16x8 b = *(const bf16x8*)&Wb[(size_t)rowb[ti] * 128 + kk * 32 + quad * 8];
            #pragma unroll
            for (int mt = 0; mt < 4; ++mt)
                acc[mt][ti] = __builtin_amdgcn_mfma_f32_16x16x32_bf16(a[mt], b, acc[mt][ti], 0, 0, 0);
        }
    }
}

__global__ __launch_bounds__(TPBM, 2)   // 2 waves/EU -> 256 unified regs/wave, no spills
void lstm_mlp_mfma(const float* __restrict__ tfeat,
                   const float* __restrict__ bih1, const float* __restrict__ bhh1,
                   const float* __restrict__ w0,  const float* __restrict__ b0,
                   const float* __restrict__ b1,
                   const unsigned short* __restrict__ wsb,
                   float* __restrict__ out)
{
    // LDS layout (double-buffered h-states; later phases alias dead buffers):
    //   hA0[2]: [0,16K) [16K,32K)   h0 ping-pong (A-layout, K=128)
    //   hA1[2]: [32K,48K) [48K,64K) h1 ping-pong
    //   mhA  : alias [0,32K)        mlp hidden (A-layout, K=256)
    //   xbh  : [65536,67072)        [64][12] bf16 trajectory (dead by epilogue)
    //   f5   : [67072,69120)        [64][8] f32 features 0..4
    //   outb : alias [0,66544)      epilogue staging, stride 260 (f5 preserved)
    __shared__ __align__(16) char smem[69120];
    unsigned short* hA0_0 = (unsigned short*)smem;
    unsigned short* hA0_1 = (unsigned short*)(smem + 16384);
    unsigned short* hA1_0 = (unsigned short*)(smem + 32768);
    unsigned short* hA1_1 = (unsigned short*)(smem + 49152);
    unsigned short* mhA   = (unsigned short*)smem;
    unsigned short* xbh   = (unsigned short*)(smem + 65536);
    float (*f5)[8]  = (float(*)[8])(smem + 67072);
    float* outb = (float*)smem;

    const int tid  = threadIdx.x;
    const int w    = tid >> 6;        // 8 waves
    const int lane = tid & 63;
    const int col  = lane & 15;
    const int quad = lane >> 4;
    const int base = blockIdx.x * MTRK;

    // ---- stage per-track inputs (traj as bf16, feats 0..4 as f32) ----
    for (int idx = tid; idx < MTRK * 12; idx += TPBM) {
        int tl = idx & 63, f = idx >> 6;
        int n = base + tl, b = n / NTRK, tt = n - b * NTRK;
        xbh[tl * 12 + f] = f2b(tfeat[(size_t)(b * 18 + 6 + f) * NTRK + tt]);
    }
    if (tid < MTRK * 5) {
        int tl = tid & 63, f = tid >> 6;
        int n = base + tl, b = n / NTRK, tt = n - b * NTRK;
        f5[tl][f] = tfeat[(size_t)(b * 18 + f) * NTRK + tt];
    }
    __syncthreads();

    const unsigned short* Whh0b = wsb + WHH0_OFF;
    const unsigned short* Wih1b = wsb + WIH1_OFF;
    const unsigned short* Whh1b = wsb + WHH1_OFF;
    const unsigned short* w0b   = wsb + W0B_OFF;
    const unsigned short* w1b   = wsb + W1B_OFF;
    const unsigned short* Bx    = wsb + BX_OFF;

    // wave w owns gate rows n = g*128 + w*16 + col (one 16-tile per gate)
    int   rowg[4];
    float bs1[4];
    #pragma unroll
    for (int g = 0; g < 4; ++g) {
        int n = g * 128 + w * 16 + col;
        rowg[g] = n;
        bs1[g] = bih1[n] + bhh1[n];
    }

    f32x4 c0[4], c1[4];
    #pragma unroll
    for (int mt = 0; mt < 4; ++mt)
        #pragma unroll
        for (int r = 0; r < 4; ++r) { c0[mt][r] = 0.0f; c1[mt][r] = 0.0f; }

    const int u = w * 16 + col;   // hidden unit this lane produces

    // Per t-step: 2 phases, 2 barriers (ping-pong h buffers).
    for (int t = 0; t < TSTEPS; ++t) {
        const int cur = t & 1;
        unsigned short* h0c       = cur ? hA0_1 : hA0_0;
        const unsigned short* h0p = cur ? hA0_0 : hA0_1;
        unsigned short* h1c       = cur ? hA1_1 : hA1_0;
        const unsigned short* h1p = cur ? hA1_0 : hA1_1;

        // ---------- layer 0: gates = [x0,x1,1]·Bx + h0_prev·Whh0 ----------
        f32x4 acc[4][4];
        {
            bf16x8 ax[4];
            #pragma unroll
            for (int mt = 0; mt < 4; ++mt) {
                bf16x8 a;
                #pragma unroll
                for (int j = 0; j < 8; ++j) a[j] = (__bf16)0.0f;
                if (quad == 0) {
                    int m = mt * 16 + col;
                    a[0] = *(const __bf16*)&xbh[m * 12 + 2 * t];
                    a[1] = *(const __bf16*)&xbh[m * 12 + 2 * t + 1];
                    a[2] = (__bf16)1.0f;
                }
                ax[mt] = a;
            }
            #pragma unroll
            for (int g = 0; g < 4; ++g) {
                bf16x8 bx;
                #pragma unroll
                for (int j = 0; j < 8; ++j) bx[j] = (__bf16)0.0f;
                if (quad == 0) bx = *(const bf16x8*)&Bx[rowg[g] * 8];
                #pragma unroll
                for (int mt = 0; mt < 4; ++mt) {
                    f32x4 z = {0.0f, 0.0f, 0.0f, 0.0f};
                    acc[mt][g] = __builtin_amdgcn_mfma_f32_16x16x32_bf16(ax[mt], bx, z, 0, 0, 0);
                }
            }
        }
        if (t > 0) accum4<4>(acc, Whh0b, h0p, rowg, lane, quad);
        #pragma unroll
        for (int mt = 0; mt < 4; ++mt)
            #pragma unroll
            for (int r = 0; r < 4; ++r) {
                float iv = sigf(acc[mt][0][r]);
                float fv = sigf(acc[mt][1][r]);
                float gv = tanhfast(acc[mt][2][r]);
                float ov = sigf(acc[mt][3][r]);
                float cn = fv * c0[mt][r] + iv * gv;
                c0[mt][r] = cn;
                int m = mt * 16 + quad * 4 + r;
                h0c[aoff4(m, u)] = f2b(ov * tanhfast(cn));
            }
        __syncthreads();   // B1: new h0 visible; h0p reads done

        // ---------- layer 1: gates = h0_new·Wih1 + h1_prev·Whh1 + bs1 ----------
        #pragma unroll
        for (int mt = 0; mt < 4; ++mt)
            #pragma unroll
            for (int g = 0; g < 4; ++g)
                #pragma unroll
                for (int r = 0; r < 4; ++r) acc[mt][g][r] = bs1[g];
        accum4<4>(acc, Wih1b, h0c, rowg, lane, quad);
        if (t > 0) accum4<4>(acc, Whh1b, h1p, rowg, lane, quad);
        #pragma unroll
        for (int mt = 0; mt < 4; ++mt)
            #pragma unroll
            for (int r = 0; r < 4; ++r) {
                float iv = sigf(acc[mt][0][r]);
                float fv = sigf(acc[mt][1][r]);
                float gv = tanhfast(acc[mt][2][r]);
                float ov = sigf(acc[mt][3][r]);
                float cn = fv * c1[mt][r] + iv * gv;
                c1[mt][r] = cn;
                int m = mt * 16 + quad * 4 + r;
                h1c[aoff4(m, u)] = f2b(ov * tanhfast(cn));
            }
        __syncthreads();   // B2: new h1 visible; h1p reads done
    }

    const unsigned short* h1f = hA1_1;   // TSTEPS=6 -> final cur=1

    // rows of the 256-wide MLP owned by this wave
    int rowm[2];
    #pragma unroll
    for (int ti = 0; ti < 2; ++ti) rowm[ti] = w * 32 + ti * 16 + col;

    // ---------- MLP layer A: mh = relu([f3, h1] @ w0^T + b0) ----------
    {
        f32x4 am[4][2];
        #pragma unroll
        for (int ti = 0; ti < 2; ++ti) {
            int n = rowm[ti];
            float bm  = b0[n];
            float wf0 = w0[n * 131 + 0], wf1 = w0[n * 131 + 1], wf2 = w0[n * 131 + 2];
            #pragma unroll
            for (int mt = 0; mt < 4; ++mt)
                #pragma unroll
                for (int r = 0; r < 4; ++r) {
                    int m = mt * 16 + quad * 4 + r;
                    am[mt][ti][r] = bm + f5[m][0] * wf0 + f5[m][1] * wf1 + f5[m][2] * wf2;
                }
        }
        accum4<2>(am, w0b, h1f, rowm, lane, quad);
        // mhA aliases the (dead) hA0 buffers [0,32K); disjoint from h1f [48K,64K).
        #pragma unroll
        for (int mt = 0; mt < 4; ++mt)
            #pragma unroll
            for (int ti = 0; ti < 2; ++ti)
                #pragma unroll
                for (int r = 0; r < 4; ++r) {
                    int m = mt * 16 + quad * 4 + r;
                    mhA[aoff8(m, w * 32 + ti * 16 + col)] = f2b(fmaxf(am[mt][ti][r], 0.0f));
                }
        __syncthreads();   // B3: mh visible
    }

    // ---------- MLP layer B: out = mh @ w1^T + b1 ----------
    {
        f32x4 ao[4][2];
        #pragma unroll
        for (int ti = 0; ti < 2; ++ti) {
            float bv = b1[rowm[ti]];
            #pragma unroll
            for (int mt = 0; mt < 4; ++mt)
                #pragma unroll
                for (int r = 0; r < 4; ++r) ao[mt][ti][r] = bv;
        }
        #pragma unroll
        for (int kk = 0; kk < 8; ++kk) {
            bf16x8 a[4];
            #pragma unroll
            for (int mt = 0; mt < 4; ++mt)
                a[mt] = *(const bf16x8*)&mhA[((mt * 8 + kk) * 64 + lane) * 8];
            #pragma unroll
            for (int ti = 0; ti < 2; ++ti) {
                bf16x8 b = *(const bf16x8*)&w1b[(size_t)rowm[ti] * 256 + kk * 32 + quad * 8];
                #pragma unroll
                for (int mt = 0; mt < 4; ++mt)
                    ao[mt][ti] = __builtin_amdgcn_mfma_f32_16x16x32_bf16(a[mt], b, ao[mt][ti], 0, 0, 0);
            }
        }
        __syncthreads();   // B4: all mhA reads complete; LDS reusable as outb

        // stage in LDS (stride 260 floats)
        #pragma unroll
        for (int mt = 0; mt < 4; ++mt)
            #pragma unroll
            for (int ti = 0; ti < 2; ++ti)
                #pragma unroll
                for (int r = 0; r < 4; ++r)
                    outb[(mt * 16 + quad * 4 + r) * 260 + w * 32 + ti * 16 + col] = ao[mt][ti][r];
        __syncthreads();   // B5

        // fully-coalesced nontemporal stores: 16 B/lane
        for (int i = tid; i < MTRK * 64; i += TPBM) {
            int row = i >> 6, c4 = (i & 63) << 2;
            f32x4 v = *(const f32x4*)&outb[row * 260 + c4];
            __builtin_nontemporal_store(v, (f32x4*)(out + (size_t)(base + row) * HID + c4));
        }
    }

    // ---------- fused pos encoding + passthrough ----------
    {
        const int tl = tid >> 3;          // 64 tracks x 8 threads
        const int ml = tid & 7;
        const int n  = base + tl;
        const float eta   = f5[tl][3];
        const float phi   = f5[tl][4];
        const float TWO_PI = 6.28318530717958647692f;
        float* o1 = out + OUT1_OFF + (size_t)n * (HID / 2);
        #pragma unroll
        for (int i = 0; i < 4; ++i) {
            int m = ml + i * 8;
            float inv = exp2f(-(float)m * (13.28771237954945f / 32.0f));
            float pe = eta * TWO_PI * inv;
            float pp = phi * TWO_PI * inv;
            f32x2 ve = { sinf(pe), cosf(pe) };
            f32x2 vp = { sinf(pp), cosf(pp) };
            __builtin_nontemporal_store(ve, (f32x2*)(o1 + 2 * m));
            __builtin_nontemporal_store(vp, (f32x2*)(o1 + 64 + 2 * m));
        }
        if (ml == 0) {
            __builtin_nontemporal_store(f5[tl][2], out + OUT2_OFF + n);
            __builtin_nontemporal_store(eta, out + OUT3_OFF + n);
            __builtin_nontemporal_store(phi, out + OUT4_OFF + n);
        }
    }
}

extern "C" void kernel_launch(void* const* d_in, const int* in_sizes, int n_in,
                              void* d_out, int out_size, void* d_ws, size_t ws_size,
                              hipStream_t stream)
{
    const float* tfeat = (const float*)d_in[0];
    const float* Wih0  = (const float*)d_in[1];
    const float* Whh0  = (const float*)d_in[2];
    const float* bih0  = (const float*)d_in[3];
    const float* bhh0  = (const float*)d_in[4];
    const float* Wih1  = (const float*)d_in[5];
    const float* Whh1  = (const float*)d_in[6];
    const float* bih1  = (const float*)d_in[7];
    const float* bhh1  = (const float*)d_in[8];
    const float* w0    = (const float*)d_in[9];
    const float* b0    = (const float*)d_in[10];
    const float* w1    = (const float*)d_in[11];
    const float* b1    = (const float*)d_in[12];
    float* out = (float*)d_out;
    unsigned short* wsb = (unsigned short*)d_ws;  // 584 KiB bf16 weights

    hipLaunchKernelGGL(prep_kernel, dim3(WS_SHORTS / TPB), dim3(TPB), 0, stream,
                       Whh0, Wih1, Whh1, w0, w1, Wih0, bih0, bhh0, wsb);
    hipLaunchKernelGGL(lstm_mlp_mfma, dim3(NBLK), dim3(TPBM), 0, stream,
                       tfeat, bih1, bhh1, w0, b0, b1, wsb, out);
}